// Round 2
// baseline (2766.952 us; speedup 1.0000x reference)
//
#include <hip/hip_runtime.h>
#include <math.h>

#define NTOK 32768      // B*T
#define DD 256
#define MM 400
#define BB 64
#define TT 512
#define TOK 32          // tokens per K1 block
#define KC 32           // K chunk

// workspace layout (bytes)
#define WS_PH     0          // float [2][64][400]  (pH sums -> normalized)
#define WS_ROWCNT 204800     // int   [2][64][400]
#define WS_HIST   409600     // int   [2][400]
#define WS_ERR    412800     // float [4]  {a_e, av_e, v_e, va_e} sums
#define WS_ZERO_BYTES 412816
#define WS_IDX    412816     // int   [2][32768]
#define WS_ESQ    674960     // float [400]
#define WS_LG     676560     // float [2][64][400]  log(pH+1e-10)
#define WS_SC     881360     // float [64][64] Scode
#define WS_MODE   897744     // int   [128]

// ---------------------------------------------------------------- e_sq
__global__ void k_esq(const float* __restrict__ emb, float* __restrict__ esq) {
    int m = blockIdx.x, lane = threadIdx.x;
    float s = 0.f;
    for (int k = lane; k < DD; k += 64) { float e = emb[m * DD + k]; s += e * e; }
    #pragma unroll
    for (int off = 1; off < 64; off <<= 1) s += __shfl_xor(s, off, 64);
    if (lane == 0) esq[m] = s;
}

// ---------------------------------------------------------------- main fused kernel
// 1024 blocks; block handles 32 tokens for BOTH modalities.
// 4 waves; wave w owns tokens {tok0..tok0+7}; lane tx owns codes m = tx+64j.
// e tile in LDS (XOR-swizzled, conflict-free b128); x read from global
// (wave-uniform addresses -> single L1/L2 fetch, off the LDS pipe).
__launch_bounds__(256, 2)
__global__ void k1_main(const float* __restrict__ a, const float* __restrict__ v,
                        const float* __restrict__ emb, const float* __restrict__ esq_g,
                        float* __restrict__ pH_g, int* __restrict__ hist,
                        int* __restrict__ rowcnt, int* __restrict__ idxws) {
    __shared__ __align__(16) float e_c[MM * KC];    // 51.2 KB
    __shared__ float pH_w[8 * MM];                  // 12.8 KB  (4 waves x 2 mods)

    const int tid = threadIdx.x;
    const int tx  = tid & 63;
    const int wv  = tid >> 6;
    const int bx  = blockIdx.x;        // 0..1023
    const int n0  = bx * TOK;
    const int b   = bx >> 4;           // batch row (16 blocks of 32 tokens per T=512)
    const int tok0 = n0 + wv * 8;

    int mj[7]; float esq[7]; int ebase[7]; int esw[7]; bool val[7];
    #pragma unroll
    for (int j = 0; j < 7; ++j) {
        int m = tx + 64 * j;
        val[j] = (m < MM);
        int mc = val[j] ? m : (MM - 1);
        mj[j] = mc;
        ebase[j] = mc * KC;
        esw[j] = mc & 7;               // XOR window swizzle
        esq[j] = esq_g[mc];
    }

    float acc[16][7];                   // [0..7]=a tokens, [8..15]=v tokens
    #pragma unroll
    for (int i = 0; i < 16; ++i)
        #pragma unroll
        for (int j = 0; j < 7; ++j) acc[i][j] = 0.f;

    for (int kc = 0; kc < DD / KC; ++kc) {
        __syncthreads();               // protect e_c reuse
        // stage e chunk: 400 rows x 32 floats = 3200 float4 slots
        for (int u = tid; u < MM * (KC / 4); u += 256) {
            int m  = u >> 3;
            int kg = u & 7;
            float4 t4 = *(const float4*)(emb + (size_t)m * DD + kc * KC + kg * 4);
            *(float4*)&e_c[m * KC + ((kg ^ (m & 7)) << 2)] = t4;
        }
        __syncthreads();

        #pragma unroll
        for (int kg = 0; kg < KC / 4; ++kg) {
            float4 eb[7];
            #pragma unroll
            for (int j = 0; j < 7; ++j)
                eb[j] = *(const float4*)&e_c[ebase[j] + ((kg ^ esw[j]) << 2)];
            const int koff = kc * KC + kg * 4;
            #pragma unroll
            for (int i = 0; i < 8; ++i) {
                float4 xa = *(const float4*)(a + (size_t)(tok0 + i) * DD + koff);
                #pragma unroll
                for (int j = 0; j < 7; ++j) {
                    acc[i][j] = fmaf(xa.x, eb[j].x, acc[i][j]);
                    acc[i][j] = fmaf(xa.y, eb[j].y, acc[i][j]);
                    acc[i][j] = fmaf(xa.z, eb[j].z, acc[i][j]);
                    acc[i][j] = fmaf(xa.w, eb[j].w, acc[i][j]);
                }
                float4 xv = *(const float4*)(v + (size_t)(tok0 + i) * DD + koff);
                #pragma unroll
                for (int j = 0; j < 7; ++j) {
                    acc[8 + i][j] = fmaf(xv.x, eb[j].x, acc[8 + i][j]);
                    acc[8 + i][j] = fmaf(xv.y, eb[j].y, acc[8 + i][j]);
                    acc[8 + i][j] = fmaf(xv.z, eb[j].z, acc[8 + i][j]);
                    acc[8 + i][j] = fmaf(xv.w, eb[j].w, acc[8 + i][j]);
                }
            }
        }
    }

    float pacc_a[7], pacc_v[7];
    #pragma unroll
    for (int j = 0; j < 7; ++j) { pacc_a[j] = 0.f; pacc_v[j] = 0.f; }

    for (int i = 0; i < 16; ++i) {
        const int mod = i >> 3;
        const int n = tok0 + (i & 7);
        const float* xg = (mod == 0) ? a : v;

        // x_sq: 64 lanes x float4 covers the 256-dim row
        float4 xr = *(const float4*)(xg + (size_t)n * DD + tx * 4);
        float xs = xr.x * xr.x + xr.y * xr.y + xr.z * xr.z + xr.w * xr.w;
        #pragma unroll
        for (int off = 1; off < 64; off <<= 1) xs += __shfl_xor(xs, off, 64);

        float sc[7];
        #pragma unroll
        for (int j = 0; j < 7; ++j) sc[j] = fmaf(-2.f, acc[i][j], esq[j]);

        // argmin (ties -> smallest index)
        float best = 1e30f; int bidx = 0x7fffffff;
        #pragma unroll
        for (int j = 0; j < 7; ++j)
            if (val[j] && sc[j] < best) { best = sc[j]; bidx = mj[j]; }
        #pragma unroll
        for (int off = 1; off < 64; off <<= 1) {
            float ob = __shfl_xor(best, off, 64);
            int   oi = __shfl_xor(bidx, off, 64);
            if (ob < best || (ob == best && oi < bidx)) { best = ob; bidx = oi; }
        }

        // softmax of z = -sqrt(max(dist,0))
        float z[7]; float zmax = -1e30f;
        #pragma unroll
        for (int j = 0; j < 7; ++j) {
            z[j] = -sqrtf(fmaxf(xs + sc[j], 0.f));
            if (val[j]) zmax = fmaxf(zmax, z[j]);
        }
        #pragma unroll
        for (int off = 1; off < 64; off <<= 1)
            zmax = fmaxf(zmax, __shfl_xor(zmax, off, 64));
        float ee[7]; float se = 0.f;
        #pragma unroll
        for (int j = 0; j < 7; ++j) {
            ee[j] = val[j] ? __expf(z[j] - zmax) : 0.f;
            se += ee[j];
        }
        #pragma unroll
        for (int off = 1; off < 64; off <<= 1) se += __shfl_xor(se, off, 64);
        float inv = 1.f / se;
        if (mod == 0) {
            #pragma unroll
            for (int j = 0; j < 7; ++j) pacc_a[j] += ee[j] * inv;
        } else {
            #pragma unroll
            for (int j = 0; j < 7; ++j) pacc_v[j] += ee[j] * inv;
        }

        if (tx == 0) {
            idxws[mod * NTOK + n] = bidx;
            atomicAdd(&hist[mod * MM + bidx], 1);
            atomicAdd(&rowcnt[(mod * BB + b) * MM + bidx], 1);
        }
    }

    // combine pH across waves, one global atomic per (mod, code)
    #pragma unroll
    for (int j = 0; j < 7; ++j)
        if (val[j]) {
            pH_w[wv * MM + mj[j]] = pacc_a[j];
            pH_w[(4 + wv) * MM + mj[j]] = pacc_v[j];
        }
    __syncthreads();
    for (int m = tid; m < MM; m += 256) {
        float sa = pH_w[m] + pH_w[MM + m] + pH_w[2 * MM + m] + pH_w[3 * MM + m];
        float sv = pH_w[4 * MM + m] + pH_w[5 * MM + m] + pH_w[6 * MM + m] + pH_w[7 * MM + m];
        atomicAdd(&pH_g[(size_t)b * MM + m], sa);
        atomicAdd(&pH_g[(size_t)(BB + b) * MM + m], sv);
    }
}

// ---------------------------------------------------------------- quantized outputs + error sums
__global__ void k_err(const float* __restrict__ a, const float* __restrict__ v,
                      const float* __restrict__ emb, const int* __restrict__ idxws,
                      float* __restrict__ out, float* __restrict__ err) {
    const int mod = blockIdx.y;
    const int tid = threadIdx.x;
    const int gid = blockIdx.x * 256 + tid;
    const int n  = gid >> 6;
    const int d4 = (gid & 63) << 2;
    const int ia = idxws[n];
    const int iv = idxws[NTOK + n];
    const int own = (mod == 0) ? ia : iv;
    const int oth = (mod == 0) ? iv : ia;
    const float* x = (mod == 0) ? a : v;

    float4 xv = *(const float4*)(x + (size_t)n * DD + d4);
    float4 qo = *(const float4*)(emb + (size_t)own * DD + d4);
    float4 qc = *(const float4*)(emb + (size_t)oth * DD + d4);
    *(float4*)(out + (size_t)mod * NTOK * DD + (size_t)n * DD + d4) = qo;

    float eo, ec;
    { float dx = xv.x - qo.x, dy = xv.y - qo.y, dz = xv.z - qo.z, dw = xv.w - qo.w;
      eo = dx * dx + dy * dy + dz * dz + dw * dw; }
    { float dx = xv.x - qc.x, dy = xv.y - qc.y, dz = xv.z - qc.z, dw = xv.w - qc.w;
      ec = dx * dx + dy * dy + dz * dz + dw * dw; }

    #pragma unroll
    for (int off = 1; off < 64; off <<= 1) {
        eo += __shfl_xor(eo, off, 64);
        ec += __shfl_xor(ec, off, 64);
    }
    __shared__ float ro[4], rc[4];
    if ((tid & 63) == 0) { ro[tid >> 6] = eo; rc[tid >> 6] = ec; }
    __syncthreads();
    if (tid == 0) {
        atomicAdd(&err[mod * 2 + 0], ro[0] + ro[1] + ro[2] + ro[3]);
        atomicAdd(&err[mod * 2 + 1], rc[0] + rc[1] + rc[2] + rc[3]);
    }
}

// ---------------------------------------------------------------- normalize pH, logs
__global__ void k2_norm(float* __restrict__ pH, float* __restrict__ Lg) {
    int i = blockIdx.x * 256 + threadIdx.x;
    if (i < 2 * BB * MM) {
        float p = pH[i] * (1.f / TT);
        pH[i] = p;
        Lg[i] = logf(p + 1e-10f);
    }
}

// ---------------------------------------------------------------- per-row mode
__global__ void k3_mode(const int* __restrict__ rowcnt, int* __restrict__ modes) {
    int r = blockIdx.x, lane = threadIdx.x;
    const int* cnt = rowcnt + r * MM;
    int bc = -1, bi = 0x7fffffff;
    for (int m = lane; m < MM; m += 64) {
        int c = cnt[m];
        if (c > bc) { bc = c; bi = m; }
    }
    #pragma unroll
    for (int off = 1; off < 64; off <<= 1) {
        int oc = __shfl_xor(bc, off, 64);
        int oi = __shfl_xor(bi, off, 64);
        if (oc > bc || (oc == bc && oi < bi)) { bc = oc; bi = oi; }
    }
    if (lane == 0) modes[r] = bi;
}

// ---------------------------------------------------------------- Scode (64x64, K=400, x2 terms)
__global__ void k4_scode(const float* __restrict__ pH, const float* __restrict__ Lg,
                         float* __restrict__ Sc) {
    int i = blockIdx.x;
    int tid = threadIdx.x, lane = tid & 63, wv = tid >> 6;
    const float* aPH = pH + (size_t)i * MM;
    const float* vPH = pH + (size_t)(BB + i) * MM;
    for (int jj = 0; jj < 16; ++jj) {
        int j = wv * 16 + jj;
        const float* Lv = Lg + (size_t)(BB + j) * MM;
        const float* La = Lg + (size_t)j * MM;
        float s = 0.f;
        for (int m = lane; m < MM; m += 64)
            s += aPH[m] * Lv[m] + vPH[m] * La[m];
        #pragma unroll
        for (int off = 1; off < 64; off <<= 1) s += __shfl_xor(s, off, 64);
        if (lane == 0) Sc[i * BB + j] = s;
    }
}

// ---------------------------------------------------------------- final scalars
__global__ void k5_final(const float* __restrict__ Sc, const int* __restrict__ hist,
                         const float* __restrict__ err, const int* __restrict__ modes,
                         float* __restrict__ outs) {
    __shared__ float red[4];
    __shared__ float mx_sh;
    int tid = threadIdx.x;
    int lane = tid & 63, wv = tid >> 6;

    float lmin = 1e30f;
    for (int i = tid; i < BB * BB; i += 256) lmin = fminf(lmin, Sc[i]);
    #pragma unroll
    for (int off = 1; off < 64; off <<= 1) lmin = fminf(lmin, __shfl_xor(lmin, off, 64));
    if (lane == 0) red[wv] = lmin;
    __syncthreads();
    if (tid == 0) mx_sh = -fminf(fminf(red[0], red[1]), fminf(red[2], red[3]));
    __syncthreads();
    float Mx = mx_sh;

    if (wv == 0) {
        int i = lane;
        float rs = 0.f;
        for (int j = 0; j < BB; ++j) rs += __expf(Sc[i * BB + j] + Mx);
        float dg = __expf(Sc[i * BB + i] + Mx);
        float term = logf(dg / (rs + 1e-5f));
        #pragma unroll
        for (int off = 1; off < 64; off <<= 1) term += __shfl_xor(term, off, 64);
        if (lane == 0) outs[4] = 0.5f * (-(term / (float)BB));
    } else if (wv == 1 || wv == 2) {
        int mod = wv - 1;
        float s = 0.f;
        for (int m = lane; m < MM; m += 64) {
            float p = (float)hist[mod * MM + m] * (1.f / (float)NTOK);
            s += p * logf(p + 1e-10f);
        }
        #pragma unroll
        for (int off = 1; off < 64; off <<= 1) s += __shfl_xor(s, off, 64);
        if (lane == 0) outs[2 + mod] = __expf(-s);
    } else {
        int eq = (modes[lane] == modes[BB + lane]) ? 1 : 0;
        #pragma unroll
        for (int off = 1; off < 64; off <<= 1) eq += __shfl_xor(eq, off, 64);
        if (lane == 0) {
            outs[5] = (float)eq;
            const float inv = 1.f / (float)((size_t)NTOK * DD);
            float a_e = err[0] * inv, av_e = err[1] * inv;
            float v_e = err[2] * inv, va_e = err[3] * inv;
            outs[0] = 0.5f * a_e + 0.25f * av_e;
            outs[1] = 0.5f * v_e + 0.25f * va_e;
        }
    }
}

// ----------------------------------------------------------------
extern "C" void kernel_launch(void* const* d_in, const int* in_sizes, int n_in,
                              void* d_out, int out_size, void* d_ws, size_t ws_size,
                              hipStream_t stream) {
    (void)in_sizes; (void)n_in; (void)out_size; (void)ws_size;
    const float* a   = (const float*)d_in[0];
    const float* v   = (const float*)d_in[1];
    const float* emb = (const float*)d_in[2];
    float* out = (float*)d_out;
    char* ws = (char*)d_ws;

    float* pH_g   = (float*)(ws + WS_PH);
    int*   rowcnt = (int*)(ws + WS_ROWCNT);
    int*   hist   = (int*)(ws + WS_HIST);
    float* err    = (float*)(ws + WS_ERR);
    int*   idxws  = (int*)(ws + WS_IDX);
    float* esq    = (float*)(ws + WS_ESQ);
    float* Lg     = (float*)(ws + WS_LG);
    float* Sc     = (float*)(ws + WS_SC);
    int*   modes  = (int*)(ws + WS_MODE);

    hipMemsetAsync(d_ws, 0, WS_ZERO_BYTES, stream);
    k_esq<<<MM, 64, 0, stream>>>(emb, esq);
    k1_main<<<1024, 256, 0, stream>>>(a, v, emb, esq, pH_g, hist, rowcnt, idxws);
    k_err<<<dim3(8192, 2), 256, 0, stream>>>(a, v, emb, idxws, out, err);
    k2_norm<<<200, 256, 0, stream>>>(pH_g, Lg);
    k3_mode<<<128, 64, 0, stream>>>(rowcnt, modes);
    k4_scode<<<BB, 256, 0, stream>>>(pH_g, Lg, Sc);
    k5_final<<<1, 256, 0, stream>>>(Sc, hist, err, modes, out + (size_t)2 * NTOK * DD);
}

// Round 3
// 1813.477 us; speedup vs baseline: 1.5258x; 1.5258x over previous
//
#include <hip/hip_runtime.h>
#include <math.h>

#define NTOK 32768      // B*T
#define DD 256
#define MM 400
#define BB 64
#define TT 512
#define TOK 32          // tokens per K1 block
#define KC 16           // K chunk

// workspace layout (bytes)
#define WS_PH     0          // float [2][64][400]
#define WS_ROWCNT 204800     // int   [2][64][400]
#define WS_ERR    409600     // float [4][64]  slotted error sums
#define WS_ZERO_BYTES 410624
#define WS_IDX    410624     // int   [2][32768]
#define WS_ESQ    672768     // float [400]
#define WS_LG     674368     // float [2][64][400]
#define WS_SC     879168     // float [64][64]
#define WS_MODE   895552     // int   [128]

// ---------------------------------------------------------------- e_sq
__global__ void k_esq(const float* __restrict__ emb, float* __restrict__ esq) {
    int m = blockIdx.x, lane = threadIdx.x;
    float s = 0.f;
    for (int k = lane; k < DD; k += 64) { float e = emb[m * DD + k]; s += e * e; }
    #pragma unroll
    for (int off = 1; off < 64; off <<= 1) s += __shfl_xor(s, off, 64);
    if (lane == 0) esq[m] = s;
}

// ---------------------------------------------------------------- main fused kernel
// 2048 blocks: one modality x 32 tokens each. 4 waves; wave owns 8 tokens;
// lane tx owns codes m = tx + 64j, j=0..6. e tile in LDS (swizzled,
// conflict-free b128); x read from global (wave-uniform addr -> one L1 line,
// VMEM pipe, off the LDS pipe). acc[8][7] = 56 hot VGPRs (no spill).
__launch_bounds__(256, 3)
__global__ void k1_main(const float* __restrict__ a, const float* __restrict__ v,
                        const float* __restrict__ emb, const float* __restrict__ esq_g,
                        float* __restrict__ pH_g,
                        int* __restrict__ rowcnt, int* __restrict__ idxws) {
    __shared__ __align__(16) float e_c[MM * KC];    // 25.6 KB
    __shared__ float pH_w[4 * MM];                  // 6.4 KB

    const int tid = threadIdx.x;
    const int tx  = tid & 63;
    const int wv  = tid >> 6;
    const int bx  = blockIdx.x;
    const int mod = bx >> 10;
    const int seg = bx & 1023;
    const int n0  = seg * TOK;
    const int b   = seg >> 4;
    const int tok0 = n0 + wv * 8;
    const float* xg = (mod == 0) ? a : v;

    int mj[7]; float esq[7]; int ebase[7]; int esw[7]; bool val[7];
    #pragma unroll
    for (int j = 0; j < 7; ++j) {
        int m = tx + 64 * j;
        val[j] = (m < MM);
        int mc = val[j] ? m : (MM - 1);
        mj[j] = mc;
        ebase[j] = mc * KC;
        esw[j] = ((mc >> 1) & 3) << 2;   // conflict-free window swizzle
        esq[j] = esq_g[mc];
    }

    float acc[8][7];
    #pragma unroll
    for (int i = 0; i < 8; ++i)
        #pragma unroll
        for (int j = 0; j < 7; ++j) acc[i][j] = 0.f;

    for (int kc = 0; kc < DD / KC; ++kc) {
        __syncthreads();
        // stage e chunk: 400 x 16 floats = 1600 float4
        for (int u = tid; u < MM * (KC / 4); u += 256) {
            int m  = u >> 2;
            int kg = u & 3;
            float4 t4 = *(const float4*)(emb + (size_t)m * DD + kc * KC + kg * 4);
            *(float4*)&e_c[m * KC + (((kg << 2) ^ (((m >> 1) & 3) << 2)))] = t4;
        }
        __syncthreads();

        #pragma unroll
        for (int kg = 0; kg < KC / 4; ++kg) {
            const int K4 = kg << 2;
            float4 eb[7];
            #pragma unroll
            for (int j = 0; j < 7; ++j)
                eb[j] = *(const float4*)&e_c[ebase[j] + (K4 ^ esw[j])];
            const int koff = kc * KC + K4;
            #pragma unroll
            for (int i = 0; i < 8; ++i) {
                float4 xa = *(const float4*)(xg + (size_t)(tok0 + i) * DD + koff);
                #pragma unroll
                for (int j = 0; j < 7; ++j) {
                    acc[i][j] = fmaf(xa.x, eb[j].x, acc[i][j]);
                    acc[i][j] = fmaf(xa.y, eb[j].y, acc[i][j]);
                    acc[i][j] = fmaf(xa.z, eb[j].z, acc[i][j]);
                    acc[i][j] = fmaf(xa.w, eb[j].w, acc[i][j]);
                }
            }
        }
    }

    float pacc[7];
    #pragma unroll
    for (int j = 0; j < 7; ++j) pacc[j] = 0.f;

    for (int i = 0; i < 8; ++i) {
        const int n = tok0 + i;

        // x_sq: 64 lanes x float4 covers the 256-dim row
        float4 xr = *(const float4*)(xg + (size_t)n * DD + tx * 4);
        float xs = xr.x * xr.x + xr.y * xr.y + xr.z * xr.z + xr.w * xr.w;
        #pragma unroll
        for (int off = 1; off < 64; off <<= 1) xs += __shfl_xor(xs, off, 64);

        float sc[7];
        #pragma unroll
        for (int j = 0; j < 7; ++j) sc[j] = fmaf(-2.f, acc[i][j], esq[j]);

        // argmin (ties -> smallest index)
        float best = 1e30f; int bidx = 0x7fffffff;
        #pragma unroll
        for (int j = 0; j < 7; ++j)
            if (val[j] && sc[j] < best) { best = sc[j]; bidx = mj[j]; }
        #pragma unroll
        for (int off = 1; off < 64; off <<= 1) {
            float ob = __shfl_xor(best, off, 64);
            int   oi = __shfl_xor(bidx, off, 64);
            if (ob < best || (ob == best && oi < bidx)) { best = ob; bidx = oi; }
        }

        // softmax of z = -sqrt(max(dist,0))
        float z[7]; float zmax = -1e30f;
        #pragma unroll
        for (int j = 0; j < 7; ++j) {
            z[j] = -sqrtf(fmaxf(xs + sc[j], 0.f));
            if (val[j]) zmax = fmaxf(zmax, z[j]);
        }
        #pragma unroll
        for (int off = 1; off < 64; off <<= 1)
            zmax = fmaxf(zmax, __shfl_xor(zmax, off, 64));
        float ee[7]; float se = 0.f;
        #pragma unroll
        for (int j = 0; j < 7; ++j) {
            ee[j] = val[j] ? __expf(z[j] - zmax) : 0.f;
            se += ee[j];
        }
        #pragma unroll
        for (int off = 1; off < 64; off <<= 1) se += __shfl_xor(se, off, 64);
        float inv = 1.f / se;
        #pragma unroll
        for (int j = 0; j < 7; ++j) pacc[j] += ee[j] * inv;

        if (tx == 0) {
            idxws[mod * NTOK + n] = bidx;
            atomicAdd(&rowcnt[(mod * BB + b) * MM + bidx], 1);
        }
    }

    // combine pH across waves, one global atomic per code
    #pragma unroll
    for (int j = 0; j < 7; ++j)
        if (val[j]) pH_w[wv * MM + mj[j]] = pacc[j];
    __syncthreads();
    for (int m = tid; m < MM; m += 256) {
        float s = pH_w[m] + pH_w[MM + m] + pH_w[2 * MM + m] + pH_w[3 * MM + m];
        atomicAdd(&pH_g[(size_t)(mod * BB + b) * MM + m], s);
    }
}

// ---------------------------------------------------------------- quantized outputs + error sums
__global__ void k_err(const float* __restrict__ a, const float* __restrict__ v,
                      const float* __restrict__ emb, const int* __restrict__ idxws,
                      float* __restrict__ out, float* __restrict__ err) {
    const int mod = blockIdx.y;
    const int tid = threadIdx.x;
    const int gid = blockIdx.x * 256 + tid;
    const int n  = gid >> 6;
    const int d4 = (gid & 63) << 2;
    const int ia = idxws[n];
    const int iv = idxws[NTOK + n];
    const int own = (mod == 0) ? ia : iv;
    const int oth = (mod == 0) ? iv : ia;
    const float* x = (mod == 0) ? a : v;

    float4 xv = *(const float4*)(x + (size_t)n * DD + d4);
    float4 qo = *(const float4*)(emb + (size_t)own * DD + d4);
    float4 qc = *(const float4*)(emb + (size_t)oth * DD + d4);
    *(float4*)(out + (size_t)mod * NTOK * DD + (size_t)n * DD + d4) = qo;

    float eo, ec;
    { float dx = xv.x - qo.x, dy = xv.y - qo.y, dz = xv.z - qo.z, dw = xv.w - qo.w;
      eo = dx * dx + dy * dy + dz * dz + dw * dw; }
    { float dx = xv.x - qc.x, dy = xv.y - qc.y, dz = xv.z - qc.z, dw = xv.w - qc.w;
      ec = dx * dx + dy * dy + dz * dz + dw * dw; }

    #pragma unroll
    for (int off = 1; off < 64; off <<= 1) {
        eo += __shfl_xor(eo, off, 64);
        ec += __shfl_xor(ec, off, 64);
    }
    __shared__ float ro[4], rc[4];
    if ((tid & 63) == 0) { ro[tid >> 6] = eo; rc[tid >> 6] = ec; }
    __syncthreads();
    if (tid == 0) {
        int slot = blockIdx.x & 63;    // 64-way slotted: contention /64
        atomicAdd(&err[(mod * 2 + 0) * 64 + slot], ro[0] + ro[1] + ro[2] + ro[3]);
        atomicAdd(&err[(mod * 2 + 1) * 64 + slot], rc[0] + rc[1] + rc[2] + rc[3]);
    }
}

// ---------------------------------------------------------------- normalize pH, logs
__global__ void k2_norm(float* __restrict__ pH, float* __restrict__ Lg) {
    int i = blockIdx.x * 256 + threadIdx.x;
    if (i < 2 * BB * MM) {
        float p = pH[i] * (1.f / TT);
        pH[i] = p;
        Lg[i] = logf(p + 1e-10f);
    }
}

// ---------------------------------------------------------------- per-row mode
__global__ void k3_mode(const int* __restrict__ rowcnt, int* __restrict__ modes) {
    int r = blockIdx.x, lane = threadIdx.x;
    const int* cnt = rowcnt + r * MM;
    int bc = -1, bi = 0x7fffffff;
    for (int m = lane; m < MM; m += 64) {
        int c = cnt[m];
        if (c > bc) { bc = c; bi = m; }
    }
    #pragma unroll
    for (int off = 1; off < 64; off <<= 1) {
        int oc = __shfl_xor(bc, off, 64);
        int oi = __shfl_xor(bi, off, 64);
        if (oc > bc || (oc == bc && oi < bi)) { bc = oc; bi = oi; }
    }
    if (lane == 0) modes[r] = bi;
}

// ---------------------------------------------------------------- Scode (64x64, K=400, x2 terms)
__global__ void k4_scode(const float* __restrict__ pH, const float* __restrict__ Lg,
                         float* __restrict__ Sc) {
    int i = blockIdx.x;
    int tid = threadIdx.x, lane = tid & 63, wv = tid >> 6;
    const float* aPH = pH + (size_t)i * MM;
    const float* vPH = pH + (size_t)(BB + i) * MM;
    for (int jj = 0; jj < 16; ++jj) {
        int j = wv * 16 + jj;
        const float* Lv = Lg + (size_t)(BB + j) * MM;
        const float* La = Lg + (size_t)j * MM;
        float s = 0.f;
        for (int m = lane; m < MM; m += 64)
            s += aPH[m] * Lv[m] + vPH[m] * La[m];
        #pragma unroll
        for (int off = 1; off < 64; off <<= 1) s += __shfl_xor(s, off, 64);
        if (lane == 0) Sc[i * BB + j] = s;
    }
}

// ---------------------------------------------------------------- final scalars
__global__ void k5_final(const float* __restrict__ Sc, const int* __restrict__ rowcnt,
                         const float* __restrict__ err, const int* __restrict__ modes,
                         float* __restrict__ outs) {
    __shared__ float red[4];
    __shared__ float mx_sh;
    int tid = threadIdx.x;
    int lane = tid & 63, wv = tid >> 6;

    float lmin = 1e30f;
    for (int i = tid; i < BB * BB; i += 256) lmin = fminf(lmin, Sc[i]);
    #pragma unroll
    for (int off = 1; off < 64; off <<= 1) lmin = fminf(lmin, __shfl_xor(lmin, off, 64));
    if (lane == 0) red[wv] = lmin;
    __syncthreads();
    if (tid == 0) mx_sh = -fminf(fminf(red[0], red[1]), fminf(red[2], red[3]));
    __syncthreads();
    float Mx = mx_sh;

    if (wv == 0) {
        int i = lane;
        float rs = 0.f;
        for (int j = 0; j < BB; ++j) rs += __expf(Sc[i * BB + j] + Mx);
        float dg = __expf(Sc[i * BB + i] + Mx);
        float term = logf(dg / (rs + 1e-5f));
        #pragma unroll
        for (int off = 1; off < 64; off <<= 1) term += __shfl_xor(term, off, 64);
        if (lane == 0) outs[4] = 0.5f * (-(term / (float)BB));
    } else if (wv == 1 || wv == 2) {
        int mod = wv - 1;
        float s = 0.f;
        for (int m = lane; m < MM; m += 64) {
            int c = 0;
            for (int bb = 0; bb < BB; ++bb)
                c += rowcnt[(size_t)(mod * BB + bb) * MM + m];
            float p = (float)c * (1.f / (float)NTOK);
            s += p * logf(p + 1e-10f);
        }
        #pragma unroll
        for (int off = 1; off < 64; off <<= 1) s += __shfl_xor(s, off, 64);
        if (lane == 0) outs[2 + mod] = __expf(-s);
    } else {
        // error sums from 64 slots each
        float e0 = err[0 * 64 + lane], e1 = err[1 * 64 + lane];
        float e2 = err[2 * 64 + lane], e3 = err[3 * 64 + lane];
        int eq = (modes[lane] == modes[BB + lane]) ? 1 : 0;
        #pragma unroll
        for (int off = 1; off < 64; off <<= 1) {
            e0 += __shfl_xor(e0, off, 64);
            e1 += __shfl_xor(e1, off, 64);
            e2 += __shfl_xor(e2, off, 64);
            e3 += __shfl_xor(e3, off, 64);
            eq += __shfl_xor(eq, off, 64);
        }
        if (lane == 0) {
            outs[5] = (float)eq;
            const float inv = 1.f / (float)((size_t)NTOK * DD);
            float a_e = e0 * inv, av_e = e1 * inv;
            float v_e = e2 * inv, va_e = e3 * inv;
            outs[0] = 0.5f * a_e + 0.25f * av_e;
            outs[1] = 0.5f * v_e + 0.25f * va_e;
        }
    }
}

// ----------------------------------------------------------------
extern "C" void kernel_launch(void* const* d_in, const int* in_sizes, int n_in,
                              void* d_out, int out_size, void* d_ws, size_t ws_size,
                              hipStream_t stream) {
    (void)in_sizes; (void)n_in; (void)out_size; (void)ws_size;
    const float* a   = (const float*)d_in[0];
    const float* v   = (const float*)d_in[1];
    const float* emb = (const float*)d_in[2];
    float* out = (float*)d_out;
    char* ws = (char*)d_ws;

    float* pH_g   = (float*)(ws + WS_PH);
    int*   rowcnt = (int*)(ws + WS_ROWCNT);
    float* err    = (float*)(ws + WS_ERR);
    int*   idxws  = (int*)(ws + WS_IDX);
    float* esq    = (float*)(ws + WS_ESQ);
    float* Lg     = (float*)(ws + WS_LG);
    float* Sc     = (float*)(ws + WS_SC);
    int*   modes  = (int*)(ws + WS_MODE);

    hipMemsetAsync(d_ws, 0, WS_ZERO_BYTES, stream);
    k_esq<<<MM, 64, 0, stream>>>(emb, esq);
    k1_main<<<2048, 256, 0, stream>>>(a, v, emb, esq, pH_g, rowcnt, idxws);
    k_err<<<dim3(8192, 2), 256, 0, stream>>>(a, v, emb, idxws, out, err);
    k2_norm<<<200, 256, 0, stream>>>(pH_g, Lg);
    k3_mode<<<128, 64, 0, stream>>>(rowcnt, modes);
    k4_scode<<<BB, 256, 0, stream>>>(pH_g, Lg, Sc);
    k5_final<<<1, 256, 0, stream>>>(Sc, rowcnt, err, modes, out + (size_t)2 * NTOK * DD);
}

// Round 4
// 1792.631 us; speedup vs baseline: 1.5435x; 1.0116x over previous
//
#include <hip/hip_runtime.h>
#include <math.h>

#define NTOK 32768      // B*T
#define DD 256
#define MM 400
#define BB 64
#define TT 512
#define TOK 32          // tokens per K1 block
#define KC 16           // K chunk

// workspace layout (bytes)
#define WS_PH     0          // float [2][64][400]
#define WS_ROWCNT 204800     // int   [2][64][400]
#define WS_ERR    409600     // float [4][64]  slotted error sums
#define WS_ZERO_BYTES 410624
#define WS_IDX    410624     // int   [2][32768]
#define WS_ESQ    672768     // float [400]
#define WS_LG     674368     // float [2][64][400]
#define WS_SC     879168     // float [64][64]
#define WS_MODE   895552     // int   [128]

// ---------------------------------------------------------------- e_sq
__global__ void k_esq(const float* __restrict__ emb, float* __restrict__ esq) {
    int m = blockIdx.x, lane = threadIdx.x;
    float s = 0.f;
    for (int k = lane; k < DD; k += 64) { float e = emb[m * DD + k]; s += e * e; }
    #pragma unroll
    for (int off = 1; off < 64; off <<= 1) s += __shfl_xor(s, off, 64);
    if (lane == 0) esq[m] = s;
}

// ---------------------------------------------------------------- main fused kernel
// 2048 blocks: one modality x 32 tokens each. 4 waves; wave owns 8 tokens;
// lane tx owns codes m = tx + 64j, j=0..6. e tile in LDS (swizzled,
// conflict-free b128); x read from global (wave-uniform addr, VMEM/SMEM pipe).
// CRITICAL: epilogue token loop is #pragma unroll so acc[][] has only static
// indices -> SROA keeps it in VGPRs. (Round 3: dynamic index -> scratch ->
// 5.5 GB of spill traffic, 14% VALUBusy.)
__launch_bounds__(256, 3)
__global__ void k1_main(const float* __restrict__ a, const float* __restrict__ v,
                        const float* __restrict__ emb, const float* __restrict__ esq_g,
                        float* __restrict__ pH_g,
                        int* __restrict__ rowcnt, int* __restrict__ idxws) {
    __shared__ __align__(16) float e_c[MM * KC];    // 25.6 KB
    __shared__ float pH_w[4 * MM];                  // 6.4 KB

    const int tid = threadIdx.x;
    const int tx  = tid & 63;
    const int wv  = tid >> 6;
    const int bx  = blockIdx.x;
    const int mod = bx >> 10;
    const int seg = bx & 1023;
    const int n0  = seg * TOK;
    const int b   = seg >> 4;
    const int tok0 = n0 + wv * 8;
    const float* xg = (mod == 0) ? a : v;

    int mj[7]; float esq[7]; int ebase[7]; int esw[7]; bool val[7];
    #pragma unroll
    for (int j = 0; j < 7; ++j) {
        int m = tx + 64 * j;
        val[j] = (m < MM);
        int mc = val[j] ? m : (MM - 1);
        mj[j] = mc;
        ebase[j] = mc * KC;
        esw[j] = ((mc >> 1) & 3) << 2;   // conflict-free window swizzle
        esq[j] = esq_g[mc];
    }

    float acc[8][7];
    #pragma unroll
    for (int i = 0; i < 8; ++i)
        #pragma unroll
        for (int j = 0; j < 7; ++j) acc[i][j] = 0.f;

    for (int kc = 0; kc < DD / KC; ++kc) {
        __syncthreads();
        // stage e chunk: 400 x 16 floats = 1600 float4
        for (int u = tid; u < MM * (KC / 4); u += 256) {
            int m  = u >> 2;
            int kg = u & 3;
            float4 t4 = *(const float4*)(emb + (size_t)m * DD + kc * KC + kg * 4);
            *(float4*)&e_c[m * KC + (((kg << 2) ^ (((m >> 1) & 3) << 2)))] = t4;
        }
        __syncthreads();

        #pragma unroll
        for (int kg = 0; kg < KC / 4; ++kg) {
            const int K4 = kg << 2;
            float4 eb[7];
            #pragma unroll
            for (int j = 0; j < 7; ++j)
                eb[j] = *(const float4*)&e_c[ebase[j] + (K4 ^ esw[j])];
            const int koff = kc * KC + K4;
            #pragma unroll
            for (int i = 0; i < 8; ++i) {
                float4 xa = *(const float4*)(xg + (size_t)(tok0 + i) * DD + koff);
                #pragma unroll
                for (int j = 0; j < 7; ++j) {
                    acc[i][j] = fmaf(xa.x, eb[j].x, acc[i][j]);
                    acc[i][j] = fmaf(xa.y, eb[j].y, acc[i][j]);
                    acc[i][j] = fmaf(xa.z, eb[j].z, acc[i][j]);
                    acc[i][j] = fmaf(xa.w, eb[j].w, acc[i][j]);
                }
            }
        }
    }

    float pacc[7];
    #pragma unroll
    for (int j = 0; j < 7; ++j) pacc[j] = 0.f;

    #pragma unroll
    for (int i = 0; i < 8; ++i) {
        const int n = tok0 + i;

        // x_sq: 64 lanes x float4 covers the 256-dim row
        float4 xr = *(const float4*)(xg + (size_t)n * DD + tx * 4);
        float xs = xr.x * xr.x + xr.y * xr.y + xr.z * xr.z + xr.w * xr.w;
        #pragma unroll
        for (int off = 1; off < 64; off <<= 1) xs += __shfl_xor(xs, off, 64);

        float sc[7];
        #pragma unroll
        for (int j = 0; j < 7; ++j) sc[j] = fmaf(-2.f, acc[i][j], esq[j]);

        // argmin (ties -> smallest index)
        float best = 1e30f; int bidx = 0x7fffffff;
        #pragma unroll
        for (int j = 0; j < 7; ++j)
            if (val[j] && sc[j] < best) { best = sc[j]; bidx = mj[j]; }
        #pragma unroll
        for (int off = 1; off < 64; off <<= 1) {
            float ob = __shfl_xor(best, off, 64);
            int   oi = __shfl_xor(bidx, off, 64);
            if (ob < best || (ob == best && oi < bidx)) { best = ob; bidx = oi; }
        }

        // softmax of z = -sqrt(max(dist,0))
        float z[7]; float zmax = -1e30f;
        #pragma unroll
        for (int j = 0; j < 7; ++j) {
            z[j] = -sqrtf(fmaxf(xs + sc[j], 0.f));
            if (val[j]) zmax = fmaxf(zmax, z[j]);
        }
        #pragma unroll
        for (int off = 1; off < 64; off <<= 1)
            zmax = fmaxf(zmax, __shfl_xor(zmax, off, 64));
        float ee[7]; float se = 0.f;
        #pragma unroll
        for (int j = 0; j < 7; ++j) {
            ee[j] = val[j] ? __expf(z[j] - zmax) : 0.f;
            se += ee[j];
        }
        #pragma unroll
        for (int off = 1; off < 64; off <<= 1) se += __shfl_xor(se, off, 64);
        float inv = 1.f / se;
        #pragma unroll
        for (int j = 0; j < 7; ++j) pacc[j] += ee[j] * inv;

        if (tx == 0) {
            idxws[mod * NTOK + n] = bidx;
            atomicAdd(&rowcnt[(mod * BB + b) * MM + bidx], 1);
        }
    }

    // combine pH across waves, one global atomic per code
    #pragma unroll
    for (int j = 0; j < 7; ++j)
        if (val[j]) pH_w[wv * MM + mj[j]] = pacc[j];
    __syncthreads();
    for (int m = tid; m < MM; m += 256) {
        float s = pH_w[m] + pH_w[MM + m] + pH_w[2 * MM + m] + pH_w[3 * MM + m];
        atomicAdd(&pH_g[(size_t)(mod * BB + b) * MM + m], s);
    }
}

// ---------------------------------------------------------------- quantized outputs + error sums
__global__ void k_err(const float* __restrict__ a, const float* __restrict__ v,
                      const float* __restrict__ emb, const int* __restrict__ idxws,
                      float* __restrict__ out, float* __restrict__ err) {
    const int mod = blockIdx.y;
    const int tid = threadIdx.x;
    const int gid = blockIdx.x * 256 + tid;
    const int n  = gid >> 6;
    const int d4 = (gid & 63) << 2;
    const int ia = idxws[n];
    const int iv = idxws[NTOK + n];
    const int own = (mod == 0) ? ia : iv;
    const int oth = (mod == 0) ? iv : ia;
    const float* x = (mod == 0) ? a : v;

    float4 xv = *(const float4*)(x + (size_t)n * DD + d4);
    float4 qo = *(const float4*)(emb + (size_t)own * DD + d4);
    float4 qc = *(const float4*)(emb + (size_t)oth * DD + d4);
    *(float4*)(out + (size_t)mod * NTOK * DD + (size_t)n * DD + d4) = qo;

    float eo, ec;
    { float dx = xv.x - qo.x, dy = xv.y - qo.y, dz = xv.z - qo.z, dw = xv.w - qo.w;
      eo = dx * dx + dy * dy + dz * dz + dw * dw; }
    { float dx = xv.x - qc.x, dy = xv.y - qc.y, dz = xv.z - qc.z, dw = xv.w - qc.w;
      ec = dx * dx + dy * dy + dz * dz + dw * dw; }

    #pragma unroll
    for (int off = 1; off < 64; off <<= 1) {
        eo += __shfl_xor(eo, off, 64);
        ec += __shfl_xor(ec, off, 64);
    }
    __shared__ float ro[4], rc[4];
    if ((tid & 63) == 0) { ro[tid >> 6] = eo; rc[tid >> 6] = ec; }
    __syncthreads();
    if (tid == 0) {
        int slot = blockIdx.x & 63;    // 64-way slotted: contention /64
        atomicAdd(&err[(mod * 2 + 0) * 64 + slot], ro[0] + ro[1] + ro[2] + ro[3]);
        atomicAdd(&err[(mod * 2 + 1) * 64 + slot], rc[0] + rc[1] + rc[2] + rc[3]);
    }
}

// ---------------------------------------------------------------- normalize pH, logs
__global__ void k2_norm(float* __restrict__ pH, float* __restrict__ Lg) {
    int i = blockIdx.x * 256 + threadIdx.x;
    if (i < 2 * BB * MM) {
        float p = pH[i] * (1.f / TT);
        pH[i] = p;
        Lg[i] = logf(p + 1e-10f);
    }
}

// ---------------------------------------------------------------- per-row mode
__global__ void k3_mode(const int* __restrict__ rowcnt, int* __restrict__ modes) {
    int r = blockIdx.x, lane = threadIdx.x;
    const int* cnt = rowcnt + r * MM;
    int bc = -1, bi = 0x7fffffff;
    for (int m = lane; m < MM; m += 64) {
        int c = cnt[m];
        if (c > bc) { bc = c; bi = m; }
    }
    #pragma unroll
    for (int off = 1; off < 64; off <<= 1) {
        int oc = __shfl_xor(bc, off, 64);
        int oi = __shfl_xor(bi, off, 64);
        if (oc > bc || (oc == bc && oi < bi)) { bc = oc; bi = oi; }
    }
    if (lane == 0) modes[r] = bi;
}

// ---------------------------------------------------------------- Scode (64x64, K=400, x2 terms)
__global__ void k4_scode(const float* __restrict__ pH, const float* __restrict__ Lg,
                         float* __restrict__ Sc) {
    int i = blockIdx.x;
    int tid = threadIdx.x, lane = tid & 63, wv = tid >> 6;
    const float* aPH = pH + (size_t)i * MM;
    const float* vPH = pH + (size_t)(BB + i) * MM;
    for (int jj = 0; jj < 16; ++jj) {
        int j = wv * 16 + jj;
        const float* Lv = Lg + (size_t)(BB + j) * MM;
        const float* La = Lg + (size_t)j * MM;
        float s = 0.f;
        for (int m = lane; m < MM; m += 64)
            s += aPH[m] * Lv[m] + vPH[m] * La[m];
        #pragma unroll
        for (int off = 1; off < 64; off <<= 1) s += __shfl_xor(s, off, 64);
        if (lane == 0) Sc[i * BB + j] = s;
    }
}

// ---------------------------------------------------------------- final scalars
__global__ void k5_final(const float* __restrict__ Sc, const int* __restrict__ rowcnt,
                         const float* __restrict__ err, const int* __restrict__ modes,
                         float* __restrict__ outs) {
    __shared__ float red[4];
    __shared__ float mx_sh;
    int tid = threadIdx.x;
    int lane = tid & 63, wv = tid >> 6;

    float lmin = 1e30f;
    for (int i = tid; i < BB * BB; i += 256) lmin = fminf(lmin, Sc[i]);
    #pragma unroll
    for (int off = 1; off < 64; off <<= 1) lmin = fminf(lmin, __shfl_xor(lmin, off, 64));
    if (lane == 0) red[wv] = lmin;
    __syncthreads();
    if (tid == 0) mx_sh = -fminf(fminf(red[0], red[1]), fminf(red[2], red[3]));
    __syncthreads();
    float Mx = mx_sh;

    if (wv == 0) {
        int i = lane;
        float rs = 0.f;
        for (int j = 0; j < BB; ++j) rs += __expf(Sc[i * BB + j] + Mx);
        float dg = __expf(Sc[i * BB + i] + Mx);
        float term = logf(dg / (rs + 1e-5f));
        #pragma unroll
        for (int off = 1; off < 64; off <<= 1) term += __shfl_xor(term, off, 64);
        if (lane == 0) outs[4] = 0.5f * (-(term / (float)BB));
    } else if (wv == 1 || wv == 2) {
        int mod = wv - 1;
        float s = 0.f;
        for (int m = lane; m < MM; m += 64) {
            int c = 0;
            for (int bb = 0; bb < BB; ++bb)
                c += rowcnt[(size_t)(mod * BB + bb) * MM + m];
            float p = (float)c * (1.f / (float)NTOK);
            s += p * logf(p + 1e-10f);
        }
        #pragma unroll
        for (int off = 1; off < 64; off <<= 1) s += __shfl_xor(s, off, 64);
        if (lane == 0) outs[2 + mod] = __expf(-s);
    } else {
        // error sums from 64 slots each
        float e0 = err[0 * 64 + lane], e1 = err[1 * 64 + lane];
        float e2 = err[2 * 64 + lane], e3 = err[3 * 64 + lane];
        int eq = (modes[lane] == modes[BB + lane]) ? 1 : 0;
        #pragma unroll
        for (int off = 1; off < 64; off <<= 1) {
            e0 += __shfl_xor(e0, off, 64);
            e1 += __shfl_xor(e1, off, 64);
            e2 += __shfl_xor(e2, off, 64);
            e3 += __shfl_xor(e3, off, 64);
            eq += __shfl_xor(eq, off, 64);
        }
        if (lane == 0) {
            outs[5] = (float)eq;
            const float inv = 1.f / (float)((size_t)NTOK * DD);
            float a_e = e0 * inv, av_e = e1 * inv;
            float v_e = e2 * inv, va_e = e3 * inv;
            outs[0] = 0.5f * a_e + 0.25f * av_e;
            outs[1] = 0.5f * v_e + 0.25f * va_e;
        }
    }
}

// ----------------------------------------------------------------
extern "C" void kernel_launch(void* const* d_in, const int* in_sizes, int n_in,
                              void* d_out, int out_size, void* d_ws, size_t ws_size,
                              hipStream_t stream) {
    (void)in_sizes; (void)n_in; (void)out_size; (void)ws_size;
    const float* a   = (const float*)d_in[0];
    const float* v   = (const float*)d_in[1];
    const float* emb = (const float*)d_in[2];
    float* out = (float*)d_out;
    char* ws = (char*)d_ws;

    float* pH_g   = (float*)(ws + WS_PH);
    int*   rowcnt = (int*)(ws + WS_ROWCNT);
    float* err    = (float*)(ws + WS_ERR);
    int*   idxws  = (int*)(ws + WS_IDX);
    float* esq    = (float*)(ws + WS_ESQ);
    float* Lg     = (float*)(ws + WS_LG);
    float* Sc     = (float*)(ws + WS_SC);
    int*   modes  = (int*)(ws + WS_MODE);

    hipMemsetAsync(d_ws, 0, WS_ZERO_BYTES, stream);
    k_esq<<<MM, 64, 0, stream>>>(emb, esq);
    k1_main<<<2048, 256, 0, stream>>>(a, v, emb, esq, pH_g, rowcnt, idxws);
    k_err<<<dim3(8192, 2), 256, 0, stream>>>(a, v, emb, idxws, out, err);
    k2_norm<<<200, 256, 0, stream>>>(pH_g, Lg);
    k3_mode<<<128, 64, 0, stream>>>(rowcnt, modes);
    k4_scode<<<BB, 256, 0, stream>>>(pH_g, Lg, Sc);
    k5_final<<<1, 256, 0, stream>>>(Sc, rowcnt, err, modes, out + (size_t)2 * NTOK * DD);
}

// Round 5
// 594.934 us; speedup vs baseline: 4.6509x; 3.0132x over previous
//
#include <hip/hip_runtime.h>
#include <math.h>

#define NTOK 32768      // B*T
#define DD 256
#define MM 400
#define BB 64
#define TT 512
#define TOK 32          // tokens per K1 block
#define KC 16           // K chunk

// workspace layout (bytes)
#define WS_PH     0          // float [2][64][400]
#define WS_ROWCNT 204800     // int   [2][64][400]
#define WS_ERR    409600     // float [4][64]  slotted error sums
#define WS_ZERO_BYTES 410624
#define WS_IDX    410624     // int   [2][32768]
#define WS_ESQ    672768     // float [400]
#define WS_LG     674368     // float [2][64][400]
#define WS_SC     879168     // float [64][64]
#define WS_MODE   895552     // int   [128]

// ---------------------------------------------------------------- e_sq
__global__ void k_esq(const float* __restrict__ emb, float* __restrict__ esq) {
    int m = blockIdx.x, lane = threadIdx.x;
    float s = 0.f;
    for (int k = lane; k < DD; k += 64) { float e = emb[m * DD + k]; s += e * e; }
    #pragma unroll
    for (int off = 1; off < 64; off <<= 1) s += __shfl_xor(s, off, 64);
    if (lane == 0) esq[m] = s;
}

// ---------------------------------------------------------------- main fused kernel
// 2048 blocks: one modality x 32 tokens each. 4 waves; wave owns 8 tokens;
// lane tx owns codes m = tx + 64j, j=0..6. e tile in LDS (swizzled,
// conflict-free b128); x read from global (wave-uniform addr, VMEM pipe).
//
// NOTE: __launch_bounds__ has NO min-waves arg. Rounds 2-4 showed that
// __launch_bounds__(256,N>=2) makes the AMDGPU promote-alloca pass refuse to
// promote acc[8][7] to VGPRs (VGPR_Count 84 << cap, GBs of scratch traffic).
// Round 1 with plain (256) promoted fine (VGPR=144). Epilogue is also
// macro-expanded so acc indices are literal constants at early-SROA time.
__launch_bounds__(256)
__global__ void k1_main(const float* __restrict__ a, const float* __restrict__ v,
                        const float* __restrict__ emb, const float* __restrict__ esq_g,
                        float* __restrict__ pH_g,
                        int* __restrict__ rowcnt, int* __restrict__ idxws) {
    __shared__ __align__(16) float e_c[MM * KC];    // 25.6 KB
    __shared__ float pH_w[4 * MM];                  // 6.4 KB

    const int tid = threadIdx.x;
    const int tx  = tid & 63;
    const int wv  = tid >> 6;
    const int bx  = blockIdx.x;
    const int mod = bx >> 10;
    const int seg = bx & 1023;
    const int n0  = seg * TOK;
    const int b   = seg >> 4;
    const int tok0 = n0 + wv * 8;
    const float* xg = (mod == 0) ? a : v;

    int mj[7]; float esq[7]; int ebase[7]; int esw[7]; bool val[7];
    #pragma unroll
    for (int j = 0; j < 7; ++j) {
        int m = tx + 64 * j;
        val[j] = (m < MM);
        int mc = val[j] ? m : (MM - 1);
        mj[j] = mc;
        ebase[j] = mc * KC;
        esw[j] = ((mc >> 1) & 3) << 2;   // conflict-free window swizzle
        esq[j] = esq_g[mc];
    }

    float acc[8][7];
    #pragma unroll
    for (int i = 0; i < 8; ++i)
        #pragma unroll
        for (int j = 0; j < 7; ++j) acc[i][j] = 0.f;

    for (int kc = 0; kc < DD / KC; ++kc) {
        __syncthreads();
        // stage e chunk: 400 x 16 floats = 1600 float4
        for (int u = tid; u < MM * (KC / 4); u += 256) {
            int m  = u >> 2;
            int kg = u & 3;
            float4 t4 = *(const float4*)(emb + (size_t)m * DD + kc * KC + kg * 4);
            *(float4*)&e_c[m * KC + (((kg << 2) ^ (((m >> 1) & 3) << 2)))] = t4;
        }
        __syncthreads();

        #pragma unroll
        for (int kg = 0; kg < KC / 4; ++kg) {
            const int K4 = kg << 2;
            float4 eb[7];
            #pragma unroll
            for (int j = 0; j < 7; ++j)
                eb[j] = *(const float4*)&e_c[ebase[j] + (K4 ^ esw[j])];
            const int koff = kc * KC + K4;
            #pragma unroll
            for (int i = 0; i < 8; ++i) {
                float4 xa = *(const float4*)(xg + (size_t)(tok0 + i) * DD + koff);
                #pragma unroll
                for (int j = 0; j < 7; ++j) {
                    acc[i][j] = fmaf(xa.x, eb[j].x, acc[i][j]);
                    acc[i][j] = fmaf(xa.y, eb[j].y, acc[i][j]);
                    acc[i][j] = fmaf(xa.z, eb[j].z, acc[i][j]);
                    acc[i][j] = fmaf(xa.w, eb[j].w, acc[i][j]);
                }
            }
        }
    }

    float pacc[7];
    #pragma unroll
    for (int j = 0; j < 7; ++j) pacc[j] = 0.f;

    // Epilogue per token, i as a LITERAL constant (macro-expanded) so the acc
    // alloca is statically indexed everywhere.
#define EPI(i) { \
        const int n = tok0 + i; \
        float4 xr = *(const float4*)(xg + (size_t)n * DD + tx * 4); \
        float xs = xr.x * xr.x + xr.y * xr.y + xr.z * xr.z + xr.w * xr.w; \
        _Pragma("unroll") \
        for (int off = 1; off < 64; off <<= 1) xs += __shfl_xor(xs, off, 64); \
        float sc[7]; \
        _Pragma("unroll") \
        for (int j = 0; j < 7; ++j) sc[j] = fmaf(-2.f, acc[i][j], esq[j]); \
        float best = 1e30f; int bidx = 0x7fffffff; \
        _Pragma("unroll") \
        for (int j = 0; j < 7; ++j) \
            if (val[j] && sc[j] < best) { best = sc[j]; bidx = mj[j]; } \
        _Pragma("unroll") \
        for (int off = 1; off < 64; off <<= 1) { \
            float ob = __shfl_xor(best, off, 64); \
            int   oi = __shfl_xor(bidx, off, 64); \
            if (ob < best || (ob == best && oi < bidx)) { best = ob; bidx = oi; } \
        } \
        float z[7]; float zmax = -1e30f; \
        _Pragma("unroll") \
        for (int j = 0; j < 7; ++j) { \
            z[j] = -sqrtf(fmaxf(xs + sc[j], 0.f)); \
            if (val[j]) zmax = fmaxf(zmax, z[j]); \
        } \
        _Pragma("unroll") \
        for (int off = 1; off < 64; off <<= 1) \
            zmax = fmaxf(zmax, __shfl_xor(zmax, off, 64)); \
        float ee[7]; float se = 0.f; \
        _Pragma("unroll") \
        for (int j = 0; j < 7; ++j) { \
            ee[j] = val[j] ? __expf(z[j] - zmax) : 0.f; \
            se += ee[j]; \
        } \
        _Pragma("unroll") \
        for (int off = 1; off < 64; off <<= 1) se += __shfl_xor(se, off, 64); \
        float inv = 1.f / se; \
        _Pragma("unroll") \
        for (int j = 0; j < 7; ++j) pacc[j] += ee[j] * inv; \
        if (tx == 0) { \
            idxws[mod * NTOK + n] = bidx; \
            atomicAdd(&rowcnt[(mod * BB + b) * MM + bidx], 1); \
        } \
    }

    EPI(0) EPI(1) EPI(2) EPI(3) EPI(4) EPI(5) EPI(6) EPI(7)
#undef EPI

    // combine pH across waves, one global atomic per code
    #pragma unroll
    for (int j = 0; j < 7; ++j)
        if (val[j]) pH_w[wv * MM + mj[j]] = pacc[j];
    __syncthreads();
    for (int m = tid; m < MM; m += 256) {
        float s = pH_w[m] + pH_w[MM + m] + pH_w[2 * MM + m] + pH_w[3 * MM + m];
        atomicAdd(&pH_g[(size_t)(mod * BB + b) * MM + m], s);
    }
}

// ---------------------------------------------------------------- quantized outputs + error sums
__global__ void k_err(const float* __restrict__ a, const float* __restrict__ v,
                      const float* __restrict__ emb, const int* __restrict__ idxws,
                      float* __restrict__ out, float* __restrict__ err) {
    const int mod = blockIdx.y;
    const int tid = threadIdx.x;
    const int gid = blockIdx.x * 256 + tid;
    const int n  = gid >> 6;
    const int d4 = (gid & 63) << 2;
    const int ia = idxws[n];
    const int iv = idxws[NTOK + n];
    const int own = (mod == 0) ? ia : iv;
    const int oth = (mod == 0) ? iv : ia;
    const float* x = (mod == 0) ? a : v;

    float4 xv = *(const float4*)(x + (size_t)n * DD + d4);
    float4 qo = *(const float4*)(emb + (size_t)own * DD + d4);
    float4 qc = *(const float4*)(emb + (size_t)oth * DD + d4);
    *(float4*)(out + (size_t)mod * NTOK * DD + (size_t)n * DD + d4) = qo;

    float eo, ec;
    { float dx = xv.x - qo.x, dy = xv.y - qo.y, dz = xv.z - qo.z, dw = xv.w - qo.w;
      eo = dx * dx + dy * dy + dz * dz + dw * dw; }
    { float dx = xv.x - qc.x, dy = xv.y - qc.y, dz = xv.z - qc.z, dw = xv.w - qc.w;
      ec = dx * dx + dy * dy + dz * dz + dw * dw; }

    #pragma unroll
    for (int off = 1; off < 64; off <<= 1) {
        eo += __shfl_xor(eo, off, 64);
        ec += __shfl_xor(ec, off, 64);
    }
    __shared__ float ro[4], rc[4];
    if ((tid & 63) == 0) { ro[tid >> 6] = eo; rc[tid >> 6] = ec; }
    __syncthreads();
    if (tid == 0) {
        int slot = blockIdx.x & 63;    // 64-way slotted: contention /64
        atomicAdd(&err[(mod * 2 + 0) * 64 + slot], ro[0] + ro[1] + ro[2] + ro[3]);
        atomicAdd(&err[(mod * 2 + 1) * 64 + slot], rc[0] + rc[1] + rc[2] + rc[3]);
    }
}

// ---------------------------------------------------------------- normalize pH, logs
__global__ void k2_norm(float* __restrict__ pH, float* __restrict__ Lg) {
    int i = blockIdx.x * 256 + threadIdx.x;
    if (i < 2 * BB * MM) {
        float p = pH[i] * (1.f / TT);
        pH[i] = p;
        Lg[i] = logf(p + 1e-10f);
    }
}

// ---------------------------------------------------------------- per-row mode
__global__ void k3_mode(const int* __restrict__ rowcnt, int* __restrict__ modes) {
    int r = blockIdx.x, lane = threadIdx.x;
    const int* cnt = rowcnt + r * MM;
    int bc = -1, bi = 0x7fffffff;
    for (int m = lane; m < MM; m += 64) {
        int c = cnt[m];
        if (c > bc) { bc = c; bi = m; }
    }
    #pragma unroll
    for (int off = 1; off < 64; off <<= 1) {
        int oc = __shfl_xor(bc, off, 64);
        int oi = __shfl_xor(bi, off, 64);
        if (oc > bc || (oc == bc && oi < bi)) { bc = oc; bi = oi; }
    }
    if (lane == 0) modes[r] = bi;
}

// ---------------------------------------------------------------- Scode (64x64, K=400, x2 terms)
__global__ void k4_scode(const float* __restrict__ pH, const float* __restrict__ Lg,
                         float* __restrict__ Sc) {
    int i = blockIdx.x;
    int tid = threadIdx.x, lane = tid & 63, wv = tid >> 6;
    const float* aPH = pH + (size_t)i * MM;
    const float* vPH = pH + (size_t)(BB + i) * MM;
    for (int jj = 0; jj < 16; ++jj) {
        int j = wv * 16 + jj;
        const float* Lv = Lg + (size_t)(BB + j) * MM;
        const float* La = Lg + (size_t)j * MM;
        float s = 0.f;
        for (int m = lane; m < MM; m += 64)
            s += aPH[m] * Lv[m] + vPH[m] * La[m];
        #pragma unroll
        for (int off = 1; off < 64; off <<= 1) s += __shfl_xor(s, off, 64);
        if (lane == 0) Sc[i * BB + j] = s;
    }
}

// ---------------------------------------------------------------- final scalars
__global__ void k5_final(const float* __restrict__ Sc, const int* __restrict__ rowcnt,
                         const float* __restrict__ err, const int* __restrict__ modes,
                         float* __restrict__ outs) {
    __shared__ float red[4];
    __shared__ float mx_sh;
    int tid = threadIdx.x;
    int lane = tid & 63, wv = tid >> 6;

    float lmin = 1e30f;
    for (int i = tid; i < BB * BB; i += 256) lmin = fminf(lmin, Sc[i]);
    #pragma unroll
    for (int off = 1; off < 64; off <<= 1) lmin = fminf(lmin, __shfl_xor(lmin, off, 64));
    if (lane == 0) red[wv] = lmin;
    __syncthreads();
    if (tid == 0) mx_sh = -fminf(fminf(red[0], red[1]), fminf(red[2], red[3]));
    __syncthreads();
    float Mx = mx_sh;

    if (wv == 0) {
        int i = lane;
        float rs = 0.f;
        for (int j = 0; j < BB; ++j) rs += __expf(Sc[i * BB + j] + Mx);
        float dg = __expf(Sc[i * BB + i] + Mx);
        float term = logf(dg / (rs + 1e-5f));
        #pragma unroll
        for (int off = 1; off < 64; off <<= 1) term += __shfl_xor(term, off, 64);
        if (lane == 0) outs[4] = 0.5f * (-(term / (float)BB));
    } else if (wv == 1 || wv == 2) {
        int mod = wv - 1;
        float s = 0.f;
        for (int m = lane; m < MM; m += 64) {
            int c = 0;
            for (int bb = 0; bb < BB; ++bb)
                c += rowcnt[(size_t)(mod * BB + bb) * MM + m];
            float p = (float)c * (1.f / (float)NTOK);
            s += p * logf(p + 1e-10f);
        }
        #pragma unroll
        for (int off = 1; off < 64; off <<= 1) s += __shfl_xor(s, off, 64);
        if (lane == 0) outs[2 + mod] = __expf(-s);
    } else {
        // error sums from 64 slots each
        float e0 = err[0 * 64 + lane], e1 = err[1 * 64 + lane];
        float e2 = err[2 * 64 + lane], e3 = err[3 * 64 + lane];
        int eq = (modes[lane] == modes[BB + lane]) ? 1 : 0;
        #pragma unroll
        for (int off = 1; off < 64; off <<= 1) {
            e0 += __shfl_xor(e0, off, 64);
            e1 += __shfl_xor(e1, off, 64);
            e2 += __shfl_xor(e2, off, 64);
            e3 += __shfl_xor(e3, off, 64);
            eq += __shfl_xor(eq, off, 64);
        }
        if (lane == 0) {
            outs[5] = (float)eq;
            const float inv = 1.f / (float)((size_t)NTOK * DD);
            float a_e = e0 * inv, av_e = e1 * inv;
            float v_e = e2 * inv, va_e = e3 * inv;
            outs[0] = 0.5f * a_e + 0.25f * av_e;
            outs[1] = 0.5f * v_e + 0.25f * va_e;
        }
    }
}

// ----------------------------------------------------------------
extern "C" void kernel_launch(void* const* d_in, const int* in_sizes, int n_in,
                              void* d_out, int out_size, void* d_ws, size_t ws_size,
                              hipStream_t stream) {
    (void)in_sizes; (void)n_in; (void)out_size; (void)ws_size;
    const float* a   = (const float*)d_in[0];
    const float* v   = (const float*)d_in[1];
    const float* emb = (const float*)d_in[2];
    float* out = (float*)d_out;
    char* ws = (char*)d_ws;

    float* pH_g   = (float*)(ws + WS_PH);
    int*   rowcnt = (int*)(ws + WS_ROWCNT);
    float* err    = (float*)(ws + WS_ERR);
    int*   idxws  = (int*)(ws + WS_IDX);
    float* esq    = (float*)(ws + WS_ESQ);
    float* Lg     = (float*)(ws + WS_LG);
    float* Sc     = (float*)(ws + WS_SC);
    int*   modes  = (int*)(ws + WS_MODE);

    hipMemsetAsync(d_ws, 0, WS_ZERO_BYTES, stream);
    k_esq<<<MM, 64, 0, stream>>>(emb, esq);
    k1_main<<<2048, 256, 0, stream>>>(a, v, emb, esq, pH_g, rowcnt, idxws);
    k_err<<<dim3(8192, 2), 256, 0, stream>>>(a, v, emb, idxws, out, err);
    k2_norm<<<200, 256, 0, stream>>>(pH_g, Lg);
    k3_mode<<<128, 64, 0, stream>>>(rowcnt, modes);
    k4_scode<<<BB, 256, 0, stream>>>(pH_g, Lg, Sc);
    k5_final<<<1, 256, 0, stream>>>(Sc, rowcnt, err, modes, out + (size_t)2 * NTOK * DD);
}